// Round 1
// baseline (632.245 us; speedup 1.0000x reference)
//
#include <hip/hip_runtime.h>

typedef __attribute__((ext_vector_type(8))) _Float16 f16x8;
typedef __attribute__((ext_vector_type(4))) float f32x4;

#define S_LEN 2048
#define DMODEL 1024
#define NHEAD 16
#define HD 64
#define QKV_LD 3072
#define BTOT 4

// ---------------- fp32 -> fp16 elementwise convert ----------------
__global__ __launch_bounds__(256) void cvt_f32_f16_k(const float* __restrict__ in,
                                                     _Float16* __restrict__ out, int n) {
  int i = (blockIdx.x * 256 + threadIdx.x) * 4;
  int stride = gridDim.x * 256 * 4;
  for (; i < n; i += stride) {
    float4 v = *(const float4*)(in + i);
    _Float16 h[4];
    h[0] = (_Float16)v.x; h[1] = (_Float16)v.y; h[2] = (_Float16)v.z; h[3] = (_Float16)v.w;
    *(uint2*)(out + i) = *(const uint2*)h;
  }
}

// ---------------- fp32 [K][N] -> fp16 [N][K] transpose-convert ----------------
__global__ __launch_bounds__(256) void transpose_cvt_k(const float* __restrict__ W,
                                                       _Float16* __restrict__ Wt,
                                                       int K, int N) {
  __shared__ float t[32][33];
  int n0 = blockIdx.x * 32, k0 = blockIdx.y * 32;
  int tx = threadIdx.x, ty = threadIdx.y;  // (32,8)
#pragma unroll
  for (int i = 0; i < 32; i += 8)
    t[ty + i][tx] = W[(size_t)(k0 + ty + i) * N + n0 + tx];
  __syncthreads();
#pragma unroll
  for (int i = 0; i < 32; i += 8)
    Wt[(size_t)(n0 + ty + i) * K + k0 + tx] = (_Float16)t[tx][ty + i];
}

// ---------------- fp16 GEMM: C[M][N] = A[M][K] * Bt[N][K]^T + bias ----------------
// 128x128 tile, BK=32, 256 threads = 4 waves in 2x2, each wave 64x64 via 4x4 MFMA tiles.
template <int OUT_F32>
__global__ __launch_bounds__(256) void gemm_bt_k(const _Float16* __restrict__ A,
                                                 const _Float16* __restrict__ Bt,
                                                 const float* __restrict__ bias,
                                                 void* __restrict__ C,
                                                 int M, int N, int K) {
  __shared__ _Float16 As[128 * 32];
  __shared__ _Float16 Bs[128 * 32];
  const int tid = threadIdx.x;
  const int wid = tid >> 6, lane = tid & 63;
  const int quad = lane >> 4, l16 = lane & 15;
  const int wr = wid >> 1, wc = wid & 1;
  const int tm = blockIdx.y * 128, tn = blockIdx.x * 128;

  const int sr = tid >> 2;          // 0..63
  const int scc = (tid & 3) * 8;    // 0,8,16,24
  const _Float16* Ag = A + (size_t)(tm + sr) * K + scc;
  const _Float16* Bg = Bt + (size_t)(tn + sr) * K + scc;

  f32x4 acc[4][4] = {};

  for (int k0 = 0; k0 < K; k0 += 32) {
    uint4 a0 = *(const uint4*)(Ag + k0);
    uint4 a1 = *(const uint4*)(Ag + k0 + (size_t)64 * K);
    uint4 b0 = *(const uint4*)(Bg + k0);
    uint4 b1 = *(const uint4*)(Bg + k0 + (size_t)64 * K);
    __syncthreads();
    *(uint4*)&As[sr * 32 + scc] = a0;
    *(uint4*)&As[(sr + 64) * 32 + scc] = a1;
    *(uint4*)&Bs[sr * 32 + scc] = b0;
    *(uint4*)&Bs[(sr + 64) * 32 + scc] = b1;
    __syncthreads();

    f16x8 af[4], bf[4];
#pragma unroll
    for (int mt = 0; mt < 4; mt++)
      af[mt] = *(const f16x8*)&As[(wr * 64 + mt * 16 + l16) * 32 + quad * 8];
#pragma unroll
    for (int nt = 0; nt < 4; nt++)
      bf[nt] = *(const f16x8*)&Bs[(wc * 64 + nt * 16 + l16) * 32 + quad * 8];
#pragma unroll
    for (int mt = 0; mt < 4; mt++)
#pragma unroll
      for (int nt = 0; nt < 4; nt++)
        acc[mt][nt] = __builtin_amdgcn_mfma_f32_16x16x32_f16(af[mt], bf[nt], acc[mt][nt], 0, 0, 0);
  }

#pragma unroll
  for (int nt = 0; nt < 4; nt++) {
    int col = tn + wc * 64 + nt * 16 + l16;
    float bv = bias[col];
#pragma unroll
    for (int mt = 0; mt < 4; mt++) {
      int row = tm + wr * 64 + mt * 16 + quad * 4;
#pragma unroll
      for (int r = 0; r < 4; r++) {
        float v = acc[mt][nt][r] + bv;
        if (OUT_F32)
          ((float*)C)[(size_t)(row + r) * N + col] = v;
        else
          ((_Float16*)C)[(size_t)(row + r) * N + col] = (_Float16)v;
      }
    }
  }
}

// ---------------- fused causal flash attention ----------------
// qkv: [B][S][3*DMODEL] fp16 (q | k | v each DMODEL wide, head h at cols h*64)
// out: [B][S][DMODEL] fp16
// grid: (S/64, B*NHEAD), block 256 = 4 waves; wave w handles q rows [qt+16w, qt+16w+15]
__global__ __launch_bounds__(256) void attn_k(const _Float16* __restrict__ qkv,
                                              _Float16* __restrict__ out) {
  __shared__ _Float16 Qs[64 * 64];
  __shared__ _Float16 Ks[32 * 64];
  __shared__ _Float16 VTs[64 * 32];
  __shared__ _Float16 Ps[4][16 * 32];

  const int tid = threadIdx.x, wid = tid >> 6, lane = tid & 63;
  const int quad = lane >> 4, l16 = lane & 15;
  const int qt = blockIdx.x * 64;
  const int bh = blockIdx.y, b = bh >> 4, h = bh & 15;
  const _Float16* base = qkv + (size_t)b * S_LEN * QKV_LD;

  // load Q tile [64][64]
  {
    int r = tid >> 3, c = (tid & 7) * 8;
    *(uint4*)&Qs[r * 64 + c] =
        *(const uint4*)(base + (size_t)(qt + r) * QKV_LD + h * HD + c);
    *(uint4*)&Qs[(r + 32) * 64 + c] =
        *(const uint4*)(base + (size_t)(qt + r + 32) * QKV_LD + h * HD + c);
  }
  __syncthreads();

  f16x8 aq0 = *(const f16x8*)&Qs[(wid * 16 + l16) * 64 + quad * 8];
  f16x8 aq1 = *(const f16x8*)&Qs[(wid * 16 + l16) * 64 + 32 + quad * 8];

  float m_i[4], l_i[4];
  f32x4 o[4] = {};
#pragma unroll
  for (int r = 0; r < 4; r++) { m_i[r] = -1e30f; l_i[r] = 0.f; }

  const int nj = (qt + 64) >> 5;
  for (int j = 0; j < nj; j++) {
    // stage K tile [32][64] and V^T tile [64][32]
    {
      int r = tid >> 3, c = (tid & 7) * 8;
      const _Float16* krow = base + (size_t)(j * 32 + r) * QKV_LD + DMODEL + h * HD + c;
      *(uint4*)&Ks[r * 64 + c] = *(const uint4*)krow;
      const _Float16* vrow = base + (size_t)(j * 32 + r) * QKV_LD + 2 * DMODEL + h * HD + c;
      union { uint4 u; _Float16 hh[8]; } vv;
      vv.u = *(const uint4*)vrow;
#pragma unroll
      for (int i = 0; i < 8; i++) VTs[(c + i) * 32 + r] = vv.hh[i];
    }
    __syncthreads();

    // scores: [16 q][32 k] per wave
    f32x4 sc[2];
#pragma unroll
    for (int nt = 0; nt < 2; nt++) {
      f16x8 b0 = *(const f16x8*)&Ks[(nt * 16 + l16) * 64 + quad * 8];
      f16x8 b1 = *(const f16x8*)&Ks[(nt * 16 + l16) * 64 + 32 + quad * 8];
      f32x4 z = {};
      z = __builtin_amdgcn_mfma_f32_16x16x32_f16(aq0, b0, z, 0, 0, 0);
      sc[nt] = __builtin_amdgcn_mfma_f32_16x16x32_f16(aq1, b1, z, 0, 0, 0);
    }

    const int qrow = qt + wid * 16 + quad * 4;
    const int kcb = j * 32 + l16;
    float p0v[4], p1v[4];
#pragma unroll
    for (int r = 0; r < 4; r++) {
      float s0 = (kcb <= qrow + r) ? sc[0][r] * 0.125f : -10000.f;
      float s1 = (kcb + 16 <= qrow + r) ? sc[1][r] * 0.125f : -10000.f;
      float mx = fmaxf(s0, s1);
#pragma unroll
      for (int d = 1; d < 16; d <<= 1) mx = fmaxf(mx, __shfl_xor(mx, d, 64));
      float mnew = fmaxf(m_i[r], mx);
      float alpha = __expf(m_i[r] - mnew);
      float p0 = __expf(s0 - mnew);
      float p1 = __expf(s1 - mnew);
      p0v[r] = p0; p1v[r] = p1;
      float rs = p0 + p1;
#pragma unroll
      for (int d = 1; d < 16; d <<= 1) rs += __shfl_xor(rs, d, 64);
      l_i[r] = l_i[r] * alpha + rs;
      m_i[r] = mnew;
#pragma unroll
      for (int nt = 0; nt < 4; nt++) o[nt][r] *= alpha;
    }

    // P: C-layout -> LDS -> A-layout
#pragma unroll
    for (int r = 0; r < 4; r++) {
      Ps[wid][(quad * 4 + r) * 32 + l16] = (_Float16)p0v[r];
      Ps[wid][(quad * 4 + r) * 32 + 16 + l16] = (_Float16)p1v[r];
    }
    __syncthreads();

    f16x8 pa = *(const f16x8*)&Ps[wid][l16 * 32 + quad * 8];
#pragma unroll
    for (int nt = 0; nt < 4; nt++) {
      f16x8 vb = *(const f16x8*)&VTs[(nt * 16 + l16) * 32 + quad * 8];
      o[nt] = __builtin_amdgcn_mfma_f32_16x16x32_f16(pa, vb, o[nt], 0, 0, 0);
    }
    __syncthreads();
  }

  // epilogue: normalize and store fp16
#pragma unroll
  for (int r = 0; r < 4; r++) {
    float inv = 1.f / l_i[r];
    int row = qt + wid * 16 + quad * 4 + r;
    _Float16* orow = out + (size_t)(b * S_LEN + row) * DMODEL + h * HD;
#pragma unroll
    for (int nt = 0; nt < 4; nt++)
      orow[nt * 16 + l16] = (_Float16)(o[nt][r] * inv);
  }
}

// ---------------- launcher ----------------
extern "C" void kernel_launch(void* const* d_in, const int* in_sizes, int n_in,
                              void* d_out, int out_size, void* d_ws, size_t ws_size,
                              hipStream_t stream) {
  const float* x = (const float*)d_in[0];
  const float* w_attn = (const float*)d_in[1];
  const float* b_attn = (const float*)d_in[2];
  const float* w_proj = (const float*)d_in[3];
  const float* b_proj = (const float*)d_in[4];
  float* outp = (float*)d_out;

  char* ws = (char*)d_ws;
  _Float16* x16 = (_Float16*)ws;                           // 8192*1024*2  = 16,777,216
  _Float16* wTa = (_Float16*)(ws + 16777216);              // 3072*1024*2  =  6,291,456
  _Float16* wTp = (_Float16*)(ws + 16777216 + 6291456);    // 1024*1024*2  =  2,097,152
  _Float16* qkv = (_Float16*)(ws + 25165824);              // 8192*3072*2  = 50,331,648
  _Float16* abuf = (_Float16*)(ws + 75497472);             // 8192*1024*2  = 16,777,216

  const int nx = BTOT * S_LEN * DMODEL;  // 8,388,608

  cvt_f32_f16_k<<<8192, 256, 0, stream>>>(x, x16, nx);
  transpose_cvt_k<<<dim3(QKV_LD / 32, DMODEL / 32), dim3(32, 8), 0, stream>>>(
      w_attn, wTa, DMODEL, QKV_LD);
  transpose_cvt_k<<<dim3(DMODEL / 32, DMODEL / 32), dim3(32, 8), 0, stream>>>(
      w_proj, wTp, DMODEL, DMODEL);

  gemm_bt_k<0><<<dim3(QKV_LD / 128, BTOT * S_LEN / 128), 256, 0, stream>>>(
      x16, wTa, b_attn, qkv, BTOT * S_LEN, QKV_LD, DMODEL);

  attn_k<<<dim3(S_LEN / 64, BTOT * NHEAD), 256, 0, stream>>>(qkv, abuf);

  gemm_bt_k<1><<<dim3(DMODEL / 128, BTOT * S_LEN / 128), 256, 0, stream>>>(
      abuf, wTp, b_proj, outp, BTOT * S_LEN, DMODEL, DMODEL);
}

// Round 2
// 372.770 us; speedup vs baseline: 1.6961x; 1.6961x over previous
//
#include <hip/hip_runtime.h>

typedef __attribute__((ext_vector_type(8))) _Float16 f16x8;
typedef __attribute__((ext_vector_type(4))) float f32x4;

#define S_LEN 2048
#define DMODEL 1024
#define NHEAD 16
#define HD 64
#define QKV_LD 3072
#define BTOT 4
#define LOG2E 1.4426950408889634f

#define GLL16(g, l)                                              \
  __builtin_amdgcn_global_load_lds(                              \
      (const __attribute__((address_space(1))) void*)(g),        \
      (__attribute__((address_space(3))) void*)(l), 16, 0, 0)

// ---------------- fp32 -> fp16 elementwise convert ----------------
__global__ __launch_bounds__(256) void cvt_f32_f16_k(const float* __restrict__ in,
                                                     _Float16* __restrict__ out, int n) {
  int i = (blockIdx.x * 256 + threadIdx.x) * 4;
  int stride = gridDim.x * 256 * 4;
  for (; i < n; i += stride) {
    float4 v = *(const float4*)(in + i);
    _Float16 h[4];
    h[0] = (_Float16)v.x; h[1] = (_Float16)v.y; h[2] = (_Float16)v.z; h[3] = (_Float16)v.w;
    *(uint2*)(out + i) = *(const uint2*)h;
  }
}

// ---------------- fp32 [K][N] -> fp16 [N][K] transpose-convert ----------------
__global__ __launch_bounds__(256) void transpose_cvt_k(const float* __restrict__ W,
                                                       _Float16* __restrict__ Wt,
                                                       int K, int N) {
  __shared__ float t[32][33];
  int n0 = blockIdx.x * 32, k0 = blockIdx.y * 32;
  int tx = threadIdx.x, ty = threadIdx.y;  // (32,8)
#pragma unroll
  for (int i = 0; i < 32; i += 8)
    t[ty + i][tx] = W[(size_t)(k0 + ty + i) * N + n0 + tx];
  __syncthreads();
#pragma unroll
  for (int i = 0; i < 32; i += 8)
    Wt[(size_t)(n0 + ty + i) * K + k0 + tx] = (_Float16)t[tx][ty + i];
}

// ---------------- fp16 GEMM: C[M][N] = A[M][K] * Bt[N][K]^T + bias ----------------
// m97 structure: 128x128 tile, BK=32, global_load_lds dwordx4 staging.
template <int OUT_F32>
__global__ __launch_bounds__(256) void gemm_bt_k(const _Float16* __restrict__ A,
                                                 const _Float16* __restrict__ Bt,
                                                 const float* __restrict__ bias,
                                                 void* __restrict__ C,
                                                 int M, int N, int K) {
  __shared__ _Float16 As[128 * 32];
  __shared__ _Float16 Bs[128 * 32];
  const int tid = threadIdx.x;
  const int wid = tid >> 6, lane = tid & 63;
  const int quad = lane >> 4, l16 = lane & 15;
  const int wr = wid >> 1, wc = wid & 1;
  const int tm = blockIdx.y * 128, tn = blockIdx.x * 128;

  const int sr = tid >> 2;        // 0..63
  const int scc = (tid & 3) * 8;  // 0,8,16,24
  const _Float16* Ag = A + (size_t)(tm + sr) * K + scc;
  const _Float16* Bg = Bt + (size_t)(tn + sr) * K + scc;
  _Float16* AsW = &As[wid * 512];  // wave chunk: byte wid*1024 + lane*16 == tid*16
  _Float16* BsW = &Bs[wid * 512];

  f32x4 acc[4][4] = {};

  for (int k0 = 0; k0 < K; k0 += 32) {
    __syncthreads();
    GLL16(Ag + k0, AsW);
    GLL16(Ag + k0 + (size_t)64 * K, AsW + 2048);
    GLL16(Bg + k0, BsW);
    GLL16(Bg + k0 + (size_t)64 * K, BsW + 2048);
    __syncthreads();

    f16x8 af[4], bf[4];
#pragma unroll
    for (int mt = 0; mt < 4; mt++)
      af[mt] = *(const f16x8*)&As[(wr * 64 + mt * 16 + l16) * 32 + quad * 8];
#pragma unroll
    for (int nt = 0; nt < 4; nt++)
      bf[nt] = *(const f16x8*)&Bs[(wc * 64 + nt * 16 + l16) * 32 + quad * 8];
#pragma unroll
    for (int mt = 0; mt < 4; mt++)
#pragma unroll
      for (int nt = 0; nt < 4; nt++)
        acc[mt][nt] = __builtin_amdgcn_mfma_f32_16x16x32_f16(af[mt], bf[nt], acc[mt][nt], 0, 0, 0);
  }

#pragma unroll
  for (int nt = 0; nt < 4; nt++) {
    int col = tn + wc * 64 + nt * 16 + l16;
    float bv = bias[col];
#pragma unroll
    for (int mt = 0; mt < 4; mt++) {
      int row = tm + wr * 64 + mt * 16 + quad * 4;
#pragma unroll
      for (int r = 0; r < 4; r++) {
        float v = acc[mt][nt][r] + bv;
        if (OUT_F32)
          ((float*)C)[(size_t)(row + r) * N + col] = v;
        else
          ((_Float16*)C)[(size_t)(row + r) * N + col] = (_Float16)v;
      }
    }
  }
}

// ---------------- fused causal flash attention (S^T / O^T orientation) ----------------
// Q-tile 128 (wave = 32 q), K-tile 64, single-buffered, 2 barriers/iter.
// Scores: S^T[k][q] = K·Q^T (A=K, B=Q) -> softmax state indexed by q=l16 (2 shuffle hops).
// PV: O^T[d][q] = V^T·P^T (A=V^T, B=P^T) -> alpha rescale lane-local.
__global__ __launch_bounds__(256, 3) void attn_k(const _Float16* __restrict__ qkv,
                                                 _Float16* __restrict__ out) {
  __shared__ _Float16 Qs[128 * 64];   // 16 KB, pre-scaled by 0.125*log2e
  __shared__ _Float16 Ks[64 * 64];    // 8 KB
  __shared__ _Float16 VTs[64 * 64];   // 8 KB: VTs[d*64+k] = V[k][d] (packed-pair writes)
  __shared__ _Float16 Ps[4][32 * 72]; // 18 KB: per-wave P / epilogue buffer (pitch 72)

  const int tid = threadIdx.x, wid = tid >> 6, lane = tid & 63;
  const int quad = lane >> 4, l16 = lane & 15;
  const int qi = gridDim.x - 1 - blockIdx.x;  // longest-first for causal balance
  const int qt = qi * 128;
  const int bh = blockIdx.y, b = bh >> 4, h = bh & 15;
  const _Float16* base = qkv + (size_t)b * S_LEN * QKV_LD + h * HD;

  // load Q tile [128][64], pre-scaled (0.125 exact; log2e folds exp->exp2)
  {
    int r = tid >> 3, c = (tid & 7) * 8;
    const _Float16 qs = (_Float16)(0.125f * LOG2E);
#pragma unroll
    for (int rr = 0; rr < 128; rr += 32) {
      union { uint4 u; f16x8 h; } v;
      v.u = *(const uint4*)(base + (size_t)(qt + r + rr) * QKV_LD + c);
      v.h *= qs;
      *(uint4*)&Qs[(r + rr) * 64 + c] = v.u;
    }
  }

  // K staging via global_load_lds: pass p covers rows p*32 + tid>>3
  const _Float16* Kg = base + DMODEL + (size_t)(tid >> 3) * QKV_LD + (tid & 7) * 8;
  _Float16* KsW0 = &Ks[wid * 512];
  _Float16* KsW1 = &Ks[2048 + wid * 512];
  // V staging (register transpose): kp fast in lane -> conflict-free dword writes
  const int kp = tid & 31, dbase = (tid >> 5) * 8;
  const _Float16* Vg = base + 2 * DMODEL + (size_t)(2 * kp) * QKV_LD + dbase;

  float m_i[2] = {-1e30f, -1e30f}, l_i[2] = {0.f, 0.f};
  f32x4 o[4][2] = {};  // O^T: o[md][nt], rows d=md*16+quad*4+r, cols q=nt*16+l16

  const int qmin_w = qt + wid * 32;
  const int qmax_w = qmin_w + 31;
  const int nj = qt / 64 + 2;

  for (int j = 0; j < nj; j++) {
    const int k0g = j * 64;
    // V loads issued before the barrier (global, no LDS hazard)
    uint4 v0 = *(const uint4*)(Vg + (size_t)k0g * QKV_LD);
    uint4 v1 = *(const uint4*)(Vg + (size_t)(k0g + 1) * QKV_LD);
    __syncthreads();  // all waves done reading previous K/V tile
    GLL16(Kg + (size_t)k0g * QKV_LD, KsW0);
    GLL16(Kg + (size_t)(k0g + 32) * QKV_LD, KsW1);
    {
      union { uint4 u; _Float16 h[8]; } a, c;
      a.u = v0; c.u = v1;
      uint* VT32 = (uint*)VTs;
#pragma unroll
      for (int i = 0; i < 8; i++) {
        union { _Float16 h[2]; uint u; } w;
        w.h[0] = a.h[i]; w.h[1] = c.h[i];
        VT32[(dbase + i) * 32 + kp] = w.u;  // bank = kp -> 2-way (free)
      }
    }
    __syncthreads();  // drains vmcnt (gll) + lgkm (ds_write)

    if (k0g <= qmax_w) {
      // ---- scores: S^T[64k][32q] ----
      f32x4 sc[4][2] = {};
#pragma unroll
      for (int ks = 0; ks < 2; ks++) {
        f16x8 bq0 = *(const f16x8*)&Qs[(wid * 32 + l16) * 64 + ks * 32 + quad * 8];
        f16x8 bq1 = *(const f16x8*)&Qs[(wid * 32 + 16 + l16) * 64 + ks * 32 + quad * 8];
#pragma unroll
        for (int mt = 0; mt < 4; mt++) {
          f16x8 ak = *(const f16x8*)&Ks[(mt * 16 + l16) * 64 + ks * 32 + quad * 8];
          sc[mt][0] = __builtin_amdgcn_mfma_f32_16x16x32_f16(ak, bq0, sc[mt][0], 0, 0, 0);
          sc[mt][1] = __builtin_amdgcn_mfma_f32_16x16x32_f16(ak, bq1, sc[mt][1], 0, 0, 0);
        }
      }

      const bool need_mask = (k0g + 63 > qmin_w);
      float alpha[2];
#pragma unroll
      for (int nt = 0; nt < 2; nt++) {
        const int qg = qmin_w + nt * 16 + l16;
        float s[16];
#pragma unroll
        for (int mt = 0; mt < 4; mt++)
#pragma unroll
          for (int r = 0; r < 4; r++) {
            float v = sc[mt][nt][r];
            if (need_mask) {
              int kg = k0g + mt * 16 + quad * 4 + r;
              v = (kg <= qg) ? v : -3.0e38f;
            }
            s[mt * 4 + r] = v;
          }
        float mx = s[0];
#pragma unroll
        for (int i = 1; i < 16; i++) mx = fmaxf(mx, s[i]);
        mx = fmaxf(mx, __shfl_xor(mx, 16, 64));
        mx = fmaxf(mx, __shfl_xor(mx, 32, 64));
        float mnew = fmaxf(m_i[nt], mx);
        alpha[nt] = __builtin_amdgcn_exp2f(m_i[nt] - mnew);
        m_i[nt] = mnew;
        float rs = 0.f;
        _Float16 ph[16];
#pragma unroll
        for (int i = 0; i < 16; i++) {
          float p = __builtin_amdgcn_exp2f(s[i] - mnew);
          rs += p;
          ph[i] = (_Float16)p;
        }
        rs += __shfl_xor(rs, 16, 64);
        rs += __shfl_xor(rs, 32, 64);
        l_i[nt] = l_i[nt] * alpha[nt] + rs;
        // P^T quad-transpose via per-wave LDS (no barrier: DS ops wave-ordered)
#pragma unroll
        for (int mt = 0; mt < 4; mt++)
          *(uint2*)&Ps[wid][(nt * 16 + l16) * 72 + mt * 16 + quad * 4] = *(uint2*)&ph[mt * 4];
      }
      // rescale O^T (alpha already in the right lane: col q = nt*16+l16)
#pragma unroll
      for (int md = 0; md < 4; md++) {
        o[md][0] *= alpha[0];
        o[md][1] *= alpha[1];
      }
      // ---- PV: O^T += V^T · P^T ----
#pragma unroll
      for (int ks = 0; ks < 2; ks++) {
        f16x8 bp0 = *(const f16x8*)&Ps[wid][l16 * 72 + ks * 32 + quad * 8];
        f16x8 bp1 = *(const f16x8*)&Ps[wid][(16 + l16) * 72 + ks * 32 + quad * 8];
#pragma unroll
        for (int md = 0; md < 4; md++) {
          f16x8 av = *(const f16x8*)&VTs[(md * 16 + l16) * 64 + ks * 32 + quad * 8];
          o[md][0] = __builtin_amdgcn_mfma_f32_16x16x32_f16(av, bp0, o[md][0], 0, 0, 0);
          o[md][1] = __builtin_amdgcn_mfma_f32_16x16x32_f16(av, bp1, o[md][1], 0, 0, 0);
        }
      }
    }
  }

  // epilogue: normalize, transpose O^T->O via per-wave LDS, coalesced store
#pragma unroll
  for (int nt = 0; nt < 2; nt++) {
    float inv = 1.0f / l_i[nt];
#pragma unroll
    for (int md = 0; md < 4; md++) {
      _Float16 hh[4];
#pragma unroll
      for (int r = 0; r < 4; r++) hh[r] = (_Float16)(o[md][nt][r] * inv);
      *(uint2*)&Ps[wid][(nt * 16 + l16) * 72 + md * 16 + quad * 4] = *(uint2*)hh;
    }
  }
  {
    int r = lane >> 1, ch = (lane & 1) * 32;
    const int qg = qt + wid * 32 + r;
    _Float16* orow = out + (size_t)(b * S_LEN + qg) * DMODEL + h * HD + ch;
#pragma unroll
    for (int i = 0; i < 4; i++)
      *(uint4*)(orow + i * 8) = *(const uint4*)&Ps[wid][r * 72 + ch + i * 8];
  }
}

// ---------------- launcher ----------------
extern "C" void kernel_launch(void* const* d_in, const int* in_sizes, int n_in,
                              void* d_out, int out_size, void* d_ws, size_t ws_size,
                              hipStream_t stream) {
  const float* x = (const float*)d_in[0];
  const float* w_attn = (const float*)d_in[1];
  const float* b_attn = (const float*)d_in[2];
  const float* w_proj = (const float*)d_in[3];
  const float* b_proj = (const float*)d_in[4];
  float* outp = (float*)d_out;

  char* ws = (char*)d_ws;
  _Float16* x16 = (_Float16*)ws;                         // 16,777,216 B
  _Float16* wTa = (_Float16*)(ws + 16777216);            //  6,291,456 B
  _Float16* wTp = (_Float16*)(ws + 16777216 + 6291456);  //  2,097,152 B
  _Float16* qkv = (_Float16*)(ws + 25165824);            // 50,331,648 B
  _Float16* abuf = (_Float16*)(ws + 75497472);           // 16,777,216 B

  const int nx = BTOT * S_LEN * DMODEL;

  cvt_f32_f16_k<<<8192, 256, 0, stream>>>(x, x16, nx);
  transpose_cvt_k<<<dim3(QKV_LD / 32, DMODEL / 32), dim3(32, 8), 0, stream>>>(
      w_attn, wTa, DMODEL, QKV_LD);
  transpose_cvt_k<<<dim3(DMODEL / 32, DMODEL / 32), dim3(32, 8), 0, stream>>>(
      w_proj, wTp, DMODEL, DMODEL);

  gemm_bt_k<0><<<dim3(QKV_LD / 128, BTOT * S_LEN / 128), 256, 0, stream>>>(
      x16, wTa, b_attn, qkv, BTOT * S_LEN, QKV_LD, DMODEL);

  attn_k<<<dim3(S_LEN / 128, BTOT * NHEAD), 256, 0, stream>>>(qkv, abuf);

  gemm_bt_k<1><<<dim3(DMODEL / 128, BTOT * S_LEN / 128), 256, 0, stream>>>(
      abuf, wTp, b_proj, outp, BTOT * S_LEN, DMODEL, DMODEL);
}

// Round 3
// 350.343 us; speedup vs baseline: 1.8046x; 1.0640x over previous
//
#include <hip/hip_runtime.h>

typedef __attribute__((ext_vector_type(8))) _Float16 f16x8;
typedef __attribute__((ext_vector_type(4))) float f32x4;

#define S_LEN 2048
#define DMODEL 1024
#define NHEAD 16
#define HD 64
#define QKV_LD 3072
#define BTOT 4
#define LOG2E 1.4426950408889634f

#define GLL16(g, l)                                              \
  __builtin_amdgcn_global_load_lds(                              \
      (const __attribute__((address_space(1))) void*)(g),        \
      (__attribute__((address_space(3))) void*)(l), 16, 0, 0)

// ---------------- fp32 -> fp16 elementwise convert ----------------
__global__ __launch_bounds__(256) void cvt_f32_f16_k(const float* __restrict__ in,
                                                     _Float16* __restrict__ out, int n) {
  int i = (blockIdx.x * 256 + threadIdx.x) * 4;
  int stride = gridDim.x * 256 * 4;
  for (; i < n; i += stride) {
    float4 v = *(const float4*)(in + i);
    _Float16 h[4];
    h[0] = (_Float16)v.x; h[1] = (_Float16)v.y; h[2] = (_Float16)v.z; h[3] = (_Float16)v.w;
    *(uint2*)(out + i) = *(const uint2*)h;
  }
}

// ---------------- fp32 [K][N] -> fp16 [N][K] transpose-convert ----------------
__global__ __launch_bounds__(256) void transpose_cvt_k(const float* __restrict__ W,
                                                       _Float16* __restrict__ Wt,
                                                       int K, int N) {
  __shared__ float t[32][33];
  int n0 = blockIdx.x * 32, k0 = blockIdx.y * 32;
  int tx = threadIdx.x, ty = threadIdx.y;  // (32,8)
#pragma unroll
  for (int i = 0; i < 32; i += 8)
    t[ty + i][tx] = W[(size_t)(k0 + ty + i) * N + n0 + tx];
  __syncthreads();
#pragma unroll
  for (int i = 0; i < 32; i += 8)
    Wt[(size_t)(n0 + ty + i) * K + k0 + tx] = (_Float16)t[tx][ty + i];
}

// ---------------- fp16 GEMM: C[M][N] = A[M][K] * Bt[N][K]^T + bias ----------------
// m97 structure: 128x128 tile, BK=32, global_load_lds dwordx4 staging.
template <int OUT_F32>
__global__ __launch_bounds__(256) void gemm_bt_k(const _Float16* __restrict__ A,
                                                 const _Float16* __restrict__ Bt,
                                                 const float* __restrict__ bias,
                                                 void* __restrict__ C,
                                                 int M, int N, int K) {
  __shared__ _Float16 As[128 * 32];
  __shared__ _Float16 Bs[128 * 32];
  const int tid = threadIdx.x;
  const int wid = tid >> 6, lane = tid & 63;
  const int quad = lane >> 4, l16 = lane & 15;
  const int wr = wid >> 1, wc = wid & 1;
  const int tm = blockIdx.y * 128, tn = blockIdx.x * 128;

  const int sr = tid >> 2;        // 0..63
  const int scc = (tid & 3) * 8;  // 0,8,16,24
  const _Float16* Ag = A + (size_t)(tm + sr) * K + scc;
  const _Float16* Bg = Bt + (size_t)(tn + sr) * K + scc;
  _Float16* AsW = &As[wid * 512];  // wave chunk: byte wid*1024 + lane*16 == tid*16
  _Float16* BsW = &Bs[wid * 512];

  f32x4 acc[4][4] = {};

  for (int k0 = 0; k0 < K; k0 += 32) {
    __syncthreads();
    GLL16(Ag + k0, AsW);
    GLL16(Ag + k0 + (size_t)64 * K, AsW + 2048);
    GLL16(Bg + k0, BsW);
    GLL16(Bg + k0 + (size_t)64 * K, BsW + 2048);
    __syncthreads();

    f16x8 af[4], bf[4];
#pragma unroll
    for (int mt = 0; mt < 4; mt++)
      af[mt] = *(const f16x8*)&As[(wr * 64 + mt * 16 + l16) * 32 + quad * 8];
#pragma unroll
    for (int nt = 0; nt < 4; nt++)
      bf[nt] = *(const f16x8*)&Bs[(wc * 64 + nt * 16 + l16) * 32 + quad * 8];
#pragma unroll
    for (int mt = 0; mt < 4; mt++)
#pragma unroll
      for (int nt = 0; nt < 4; nt++)
        acc[mt][nt] = __builtin_amdgcn_mfma_f32_16x16x32_f16(af[mt], bf[nt], acc[mt][nt], 0, 0, 0);
  }

#pragma unroll
  for (int nt = 0; nt < 4; nt++) {
    int col = tn + wc * 64 + nt * 16 + l16;
    float bv = bias[col];
#pragma unroll
    for (int mt = 0; mt < 4; mt++) {
      int row = tm + wr * 64 + mt * 16 + quad * 4;
#pragma unroll
      for (int r = 0; r < 4; r++) {
        float v = acc[mt][nt][r] + bv;
        if (OUT_F32)
          ((float*)C)[(size_t)(row + r) * N + col] = v;
        else
          ((_Float16*)C)[(size_t)(row + r) * N + col] = (_Float16)v;
      }
    }
  }
}

// ---------------- fused causal flash attention ----------------
// S^T/O^T orientation; Q in registers; double-buffered K/V prefetch;
// one barrier per K-tile.  Q-tile 128 (wave = 32 q), K-tile 64.
__global__ __launch_bounds__(256, 3) void attn_k(const _Float16* __restrict__ qkv,
                                                 _Float16* __restrict__ out) {
  __shared__ _Float16 Ks[2][32 * 64 * 2];   // 2 x 8 KB  [k][d]
  __shared__ _Float16 VTs[2][64 * 64];      // 2 x 8 KB  [d][k]
  __shared__ _Float16 Ps[4][32 * 72];       // 18 KB per-wave P^T / epilogue (pitch 72)

  const int tid = threadIdx.x, wid = tid >> 6, lane = tid & 63;
  const int quad = lane >> 4, l16 = lane & 15;
  const int qi = gridDim.x - 1 - blockIdx.x;  // longest-first for causal balance
  const int qt = qi * 128;
  const int bh = blockIdx.y, b = bh >> 4, h = bh & 15;
  const _Float16* base = qkv + (size_t)b * S_LEN * QKV_LD + h * HD;

  // ---- Q fragments in registers (B-operand layout), pre-scaled ----
  f16x8 bq[2][2];  // [nt][ks]
  {
    const _Float16 qs = (_Float16)(0.125f * LOG2E);
#pragma unroll
    for (int nt = 0; nt < 2; nt++)
#pragma unroll
      for (int ks = 0; ks < 2; ks++) {
        union { uint4 u; f16x8 h; } v;
        v.u = *(const uint4*)(base + (size_t)(qt + wid * 32 + nt * 16 + l16) * QKV_LD +
                              ks * 32 + quad * 8);
        bq[nt][ks] = v.h * qs;
      }
  }

  // K staging via global_load_lds (rows tid>>3 per pass)
  const _Float16* Kg = base + DMODEL + (size_t)(tid >> 3) * QKV_LD + (tid & 7) * 8;
  // V staging (register transpose): kp fast in lane -> 2-way (free) banking
  const int kp = tid & 31, dbase = (tid >> 5) * 8;
  const _Float16* Vg = base + 2 * DMODEL + (size_t)(2 * kp) * QKV_LD + dbase;

  float m_i[2] = {-1e30f, -1e30f}, l_i[2] = {0.f, 0.f};
  f32x4 o[4][2] = {};  // O^T: rows d=md*16+quad*4+r, cols q=nt*16+l16

  const int qmin_w = qt + wid * 32;
  const int qmax_w = qmin_w + 31;
  const int nj = qt / 64 + 2;

  // ---- prologue: stage tile 0 ----
  uint4 pv0, pv1;
  GLL16(Kg, &Ks[0][wid * 512]);
  GLL16(Kg + (size_t)32 * QKV_LD, &Ks[0][2048 + wid * 512]);
  pv0 = *(const uint4*)(Vg);
  pv1 = *(const uint4*)(Vg + QKV_LD);
  {
    union { uint4 u; _Float16 h[8]; } a, c;
    a.u = pv0; c.u = pv1;
    uint* VT32 = (uint*)VTs[0];
#pragma unroll
    for (int i = 0; i < 8; i++) {
      union { _Float16 h[2]; uint u; } w;
      w.h[0] = a.h[i]; w.h[1] = c.h[i];
      VT32[(dbase + i) * 32 + kp] = w.u;
    }
  }
  __syncthreads();

  for (int j = 0; j < nj; j++) {
    const int cur = j & 1, nxt = cur ^ 1;
    const int k0g = j * 64;
    const bool pf = (j + 1 < nj);
    if (pf) {
      const int kn = k0g + 64;
      GLL16(Kg + (size_t)kn * QKV_LD, &Ks[nxt][wid * 512]);
      GLL16(Kg + (size_t)(kn + 32) * QKV_LD, &Ks[nxt][2048 + wid * 512]);
      pv0 = *(const uint4*)(Vg + (size_t)kn * QKV_LD);
      pv1 = *(const uint4*)(Vg + (size_t)(kn + 1) * QKV_LD);
    }

    if (k0g <= qmax_w) {
      // ---- scores: S^T[64k][32q] ----
      f32x4 sc[4][2] = {};
#pragma unroll
      for (int ks = 0; ks < 2; ks++) {
#pragma unroll
        for (int mt = 0; mt < 4; mt++) {
          f16x8 ak = *(const f16x8*)&Ks[cur][(mt * 16 + l16) * 64 + ks * 32 + quad * 8];
          sc[mt][0] = __builtin_amdgcn_mfma_f32_16x16x32_f16(ak, bq[0][ks], sc[mt][0], 0, 0, 0);
          sc[mt][1] = __builtin_amdgcn_mfma_f32_16x16x32_f16(ak, bq[1][ks], sc[mt][1], 0, 0, 0);
        }
      }

      const bool need_mask = (k0g + 63 > qmin_w);
      float alpha[2];
#pragma unroll
      for (int nt = 0; nt < 2; nt++) {
        const int qg = qmin_w + nt * 16 + l16;
        float s[16];
#pragma unroll
        for (int mt = 0; mt < 4; mt++)
#pragma unroll
          for (int r = 0; r < 4; r++) {
            float v = sc[mt][nt][r];
            if (need_mask) {
              int kg = k0g + mt * 16 + quad * 4 + r;
              v = (kg <= qg) ? v : -3.0e38f;
            }
            s[mt * 4 + r] = v;
          }
        float mx = s[0];
#pragma unroll
        for (int i = 1; i < 16; i++) mx = fmaxf(mx, s[i]);
        mx = fmaxf(mx, __shfl_xor(mx, 16, 64));
        mx = fmaxf(mx, __shfl_xor(mx, 32, 64));
        float mnew = fmaxf(m_i[nt], mx);
        alpha[nt] = __builtin_amdgcn_exp2f(m_i[nt] - mnew);
        m_i[nt] = mnew;
        float rs = 0.f;
        _Float16 ph[16];
#pragma unroll
        for (int i = 0; i < 16; i++) {
          float p = __builtin_amdgcn_exp2f(s[i] - mnew);
          rs += p;
          ph[i] = (_Float16)p;
        }
        rs += __shfl_xor(rs, 16, 64);
        rs += __shfl_xor(rs, 32, 64);
        l_i[nt] = l_i[nt] * alpha[nt] + rs;
        // P^T quad-transpose via per-wave LDS (no barrier: DS wave-ordered)
#pragma unroll
        for (int mt = 0; mt < 4; mt++)
          *(uint2*)&Ps[wid][(nt * 16 + l16) * 72 + mt * 16 + quad * 4] = *(uint2*)&ph[mt * 4];
      }
#pragma unroll
      for (int md = 0; md < 4; md++) {
        o[md][0] *= alpha[0];
        o[md][1] *= alpha[1];
      }
      // ---- PV: O^T += V^T · P^T ----
#pragma unroll
      for (int ks = 0; ks < 2; ks++) {
        f16x8 bp0 = *(const f16x8*)&Ps[wid][l16 * 72 + ks * 32 + quad * 8];
        f16x8 bp1 = *(const f16x8*)&Ps[wid][(16 + l16) * 72 + ks * 32 + quad * 8];
#pragma unroll
        for (int md = 0; md < 4; md++) {
          f16x8 av = *(const f16x8*)&VTs[cur][(md * 16 + l16) * 64 + ks * 32 + quad * 8];
          o[md][0] = __builtin_amdgcn_mfma_f32_16x16x32_f16(av, bp0, o[md][0], 0, 0, 0);
          o[md][1] = __builtin_amdgcn_mfma_f32_16x16x32_f16(av, bp1, o[md][1], 0, 0, 0);
        }
      }
    }

    if (pf) {
      union { uint4 u; _Float16 h[8]; } a, c;
      a.u = pv0; c.u = pv1;
      uint* VT32 = (uint*)VTs[nxt];
#pragma unroll
      for (int i = 0; i < 8; i++) {
        union { _Float16 h[2]; uint u; } w;
        w.h[0] = a.h[i]; w.h[1] = c.h[i];
        VT32[(dbase + i) * 32 + kp] = w.u;
      }
    }
    __syncthreads();  // drains GLL K(j+1) + V writes; frees cur for next prefetch
  }

  // epilogue: normalize, transpose O^T->O via per-wave LDS, coalesced store
#pragma unroll
  for (int nt = 0; nt < 2; nt++) {
    float inv = 1.0f / l_i[nt];
#pragma unroll
    for (int md = 0; md < 4; md++) {
      _Float16 hh[4];
#pragma unroll
      for (int r = 0; r < 4; r++) hh[r] = (_Float16)(o[md][nt][r] * inv);
      *(uint2*)&Ps[wid][(nt * 16 + l16) * 72 + md * 16 + quad * 4] = *(uint2*)hh;
    }
  }
  {
    int r = lane >> 1, ch = (lane & 1) * 32;
    const int qg = qt + wid * 32 + r;
    _Float16* orow = out + (size_t)(b * S_LEN + qg) * DMODEL + h * HD + ch;
#pragma unroll
    for (int i = 0; i < 4; i++)
      *(uint4*)(orow + i * 8) = *(const uint4*)&Ps[wid][r * 72 + ch + i * 8];
  }
}

// ---------------- launcher ----------------
extern "C" void kernel_launch(void* const* d_in, const int* in_sizes, int n_in,
                              void* d_out, int out_size, void* d_ws, size_t ws_size,
                              hipStream_t stream) {
  const float* x = (const float*)d_in[0];
  const float* w_attn = (const float*)d_in[1];
  const float* b_attn = (const float*)d_in[2];
  const float* w_proj = (const float*)d_in[3];
  const float* b_proj = (const float*)d_in[4];
  float* outp = (float*)d_out;

  char* ws = (char*)d_ws;
  _Float16* x16 = (_Float16*)ws;                         // 16,777,216 B
  _Float16* wTa = (_Float16*)(ws + 16777216);            //  6,291,456 B
  _Float16* wTp = (_Float16*)(ws + 16777216 + 6291456);  //  2,097,152 B
  _Float16* qkv = (_Float16*)(ws + 25165824);            // 50,331,648 B
  _Float16* abuf = (_Float16*)(ws + 75497472);           // 16,777,216 B

  const int nx = BTOT * S_LEN * DMODEL;

  cvt_f32_f16_k<<<8192, 256, 0, stream>>>(x, x16, nx);
  transpose_cvt_k<<<dim3(QKV_LD / 32, DMODEL / 32), dim3(32, 8), 0, stream>>>(
      w_attn, wTa, DMODEL, QKV_LD);
  transpose_cvt_k<<<dim3(DMODEL / 32, DMODEL / 32), dim3(32, 8), 0, stream>>>(
      w_proj, wTp, DMODEL, DMODEL);

  gemm_bt_k<0><<<dim3(QKV_LD / 128, BTOT * S_LEN / 128), 256, 0, stream>>>(
      x16, wTa, b_attn, qkv, BTOT * S_LEN, QKV_LD, DMODEL);

  attn_k<<<dim3(S_LEN / 128, BTOT * NHEAD), 256, 0, stream>>>(qkv, abuf);

  gemm_bt_k<1><<<dim3(DMODEL / 128, BTOT * S_LEN / 128), 256, 0, stream>>>(
      abuf, wTp, b_proj, outp, BTOT * S_LEN, DMODEL, DMODEL);
}